// Round 6
// baseline (53.194 us; speedup 1.0000x reference)
//
#include <hip/hip_runtime.h>

// VectorQuantization: x (32,64,64,64) f32, embedding (512,64) f32
// out = [quantized_ste (8388608 f32)] ++ [loss (1 f32)]
//
// score[k,n] = e2[k] - 2*dot(e_k, x_n); argmin_k; gather; loss=1.25*mean dist.
// bf16 3-pass MFMA (hi*hi + lo*hi + hi*lo), packed top-2 + fp64 refine.
// Round 6: K-chunked LDS (2 x 33KB chunks -> 66KB -> 2 blocks/CU, 4 waves/SIMD),
// per-pass accumulators (MFMA chain depth 6 -> 2), grid 512.

#define C_DIM 64
#define K_EMB 512
#define KCH   (K_EMB / 2)       // 256 k per chunk
#define NVEC (32 * 64 * 64)     // 131072
#define BLK 512                 // 8 waves
#define NPB 256                 // vectors per block
#define GRID (NVEC / NPB)       // 512 = 2 blocks/CU
#define KTC 16                  // k-tiles per chunk
#define NT 2                    // 16-vector groups per wave

typedef __attribute__((ext_vector_type(8))) short bf16x8;
typedef __attribute__((ext_vector_type(4))) float f32x4;

// ws layout (bytes)
#define WS_E2   0
#define WS_EHI  4096
#define WS_ELO  (4096 + 65536)
#define WS_PART (4096 + 2 * 65536)

__device__ inline unsigned short f2bf(float f) {
    unsigned u = __float_as_uint(f);
    u += 0x7FFF + ((u >> 16) & 1);   // RNE
    return (unsigned short)(u >> 16);
}
__device__ inline float bf2f(unsigned short h) {
    return __uint_as_float(((unsigned)h) << 16);
}
__device__ inline bool lessidx(float s, int i, float t, int j) {
    return (s < t) || (s == t && i < j);
}

// ---- prep: e2[k]; frag-linear bf16 hi/lo of (-2*emb) ----
// frag layout: region r = kt*2 + s (s = K-step), lane l holds 8 bf16 =
// A[row = kt*16 + (l&15)][c = 32*s + (l>>4)*8 + j], stored at (r*64+l)*8 shorts.
__global__ __launch_bounds__(512) void vq_prep(const float* __restrict__ emb,
                                               float* __restrict__ e2,
                                               short* __restrict__ ehi,
                                               short* __restrict__ elo) {
    const int t = blockIdx.x * 512 + threadIdx.x;   // 0..4095
    const int l = t & 63;
    const int kt2 = t >> 6;                         // kt*2 + s
    const int row = (kt2 >> 1) * 16 + (l & 15);
    const int cb  = (kt2 & 1) * 32 + (l >> 4) * 8;
    const float* src = emb + row * C_DIM + cb;
    bf16x8 vh, vl;
#pragma unroll
    for (int j = 0; j < 8; ++j) {
        float v = -2.0f * src[j];
        unsigned short h = f2bf(v);
        float hf = bf2f(h);
        unsigned short q = f2bf(v - hf);
        vh[j] = (short)h;
        vl[j] = (short)q;
    }
    *(bf16x8*)(ehi + (size_t)t * 8) = vh;
    *(bf16x8*)(elo + (size_t)t * 8) = vl;

    if (t < K_EMB) {
        const float* r = emb + t * C_DIM;
        float s = 0.f;
#pragma unroll
        for (int c = 0; c < C_DIM; ++c) s += r[c] * r[c];
        e2[t] = s;
    }
}

__global__ __launch_bounds__(BLK, 4) void vq_main(
    const float* __restrict__ x,
    const float* __restrict__ emb,
    const float* __restrict__ e2g,
    const short* __restrict__ ehi_g,
    const short* __restrict__ elo_g,
    float* __restrict__ out,
    double* __restrict__ partials)
{
    __shared__ __align__(16) short s_hi[KCH * C_DIM];   // 32 KB (one chunk)
    __shared__ __align__(16) short s_lo[KCH * C_DIM];   // 32 KB
    __shared__ __align__(16) float s_e2[K_EMB];         // 2 KB
    __shared__ double s_wsum[BLK / 64];

    const int tid  = threadIdx.x;
    const int lane = tid & 63;
    const int wid  = tid >> 6;
    const int lr   = lane & 15;
    const int lh   = lane >> 4;
    const int nbase = blockIdx.x * NPB + wid * 32;

    // ---- x loads first (fly during staging) ----
    float4 xr[8];
#pragma unroll
    for (int nt = 0; nt < NT; ++nt) {
        const float* xp = x + (size_t)(nbase + nt * 16 + lr) * C_DIM;
#pragma unroll
        for (int s = 0; s < 2; ++s) {
            xr[nt * 4 + s * 2 + 0] = *(const float4*)(xp + s * 32 + lh * 8);
            xr[nt * 4 + s * 2 + 1] = *(const float4*)(xp + s * 32 + lh * 8 + 4);
        }
    }

    // ---- stage e2 + chunk 0 ----
    if (tid < K_EMB) s_e2[tid] = e2g[tid];
    {
        const float4* srch = (const float4*)ehi_g;          // chunk 0
        const float4* srcl = (const float4*)elo_g;
        float4* dsth = (float4*)s_hi;
        float4* dstl = (float4*)s_lo;
#pragma unroll
        for (int i = 0; i < 4; ++i) dsth[tid + i * BLK] = srch[tid + i * BLK];
#pragma unroll
        for (int i = 0; i < 4; ++i) dstl[tid + i * BLK] = srcl[tid + i * BLK];
    }
    __syncthreads();

    // ---- x -> B-fragments (hi/lo), x2 partials ----
    bf16x8 xh[NT][2], xl[NT][2];
    float x2p[NT];
#pragma unroll
    for (int nt = 0; nt < NT; ++nt) {
        x2p[nt] = 0.f;
#pragma unroll
        for (int s = 0; s < 2; ++s) {
            float4 a = xr[nt * 4 + s * 2 + 0];
            float4 b = xr[nt * 4 + s * 2 + 1];
            float vv[8] = {a.x, a.y, a.z, a.w, b.x, b.y, b.z, b.w};
#pragma unroll
            for (int j = 0; j < 8; ++j) {
                float v = vv[j];
                x2p[nt] += v * v;
                unsigned short h = f2bf(v);
                float hf = bf2f(h);
                unsigned short q = f2bf(v - hf);
                xh[nt][s][j] = (short)h;
                xl[nt][s][j] = (short)q;
            }
        }
    }

    float pb1[NT] = {1e30f, 1e30f}, pb2[NT] = {1e30f, 1e30f};

    // ---- two K-chunks: kloop over 16 tiles each ----
#pragma unroll 1
    for (int ch = 0; ch < 2; ++ch) {
        if (ch == 1) {
            __syncthreads();     // all waves done with chunk 0
            const float4* srch = (const float4*)ehi_g + 2048;
            const float4* srcl = (const float4*)elo_g + 2048;
            float4* dsth = (float4*)s_hi;
            float4* dstl = (float4*)s_lo;
#pragma unroll
            for (int i = 0; i < 4; ++i) dsth[tid + i * BLK] = srch[tid + i * BLK];
#pragma unroll
            for (int i = 0; i < 4; ++i) dstl[tid + i * BLK] = srcl[tid + i * BLK];
            __syncthreads();
        }
        const int ktb = ch * KTC;
        const bf16x8* hb = (const bf16x8*)s_hi + lane;
        const bf16x8* lb = (const bf16x8*)s_lo + lane;

#pragma unroll 2
        for (int kt = 0; kt < KTC; ++kt) {
            bf16x8 ah0 = hb[kt * 128], ah1 = hb[kt * 128 + 64];
            bf16x8 al0 = lb[kt * 128], al1 = lb[kt * 128 + 64];
            float4 ev = *(const float4*)(s_e2 + (ktb + kt) * 16 + lh * 4);

            // per-pass accumulators: chain depth 2, 6 independent chains
            f32x4 h0 = {ev.x, ev.y, ev.z, ev.w};
            f32x4 h1 = h0;
            f32x4 p0 = {0.f, 0.f, 0.f, 0.f};
            f32x4 p1 = p0, q0 = p0, q1 = p0;

            h0 = __builtin_amdgcn_mfma_f32_16x16x32_bf16(ah0, xh[0][0], h0, 0, 0, 0);
            h1 = __builtin_amdgcn_mfma_f32_16x16x32_bf16(ah0, xh[1][0], h1, 0, 0, 0);
            p0 = __builtin_amdgcn_mfma_f32_16x16x32_bf16(al0, xh[0][0], p0, 0, 0, 0);
            p1 = __builtin_amdgcn_mfma_f32_16x16x32_bf16(al0, xh[1][0], p1, 0, 0, 0);
            q0 = __builtin_amdgcn_mfma_f32_16x16x32_bf16(ah0, xl[0][0], q0, 0, 0, 0);
            q1 = __builtin_amdgcn_mfma_f32_16x16x32_bf16(ah0, xl[1][0], q1, 0, 0, 0);
            h0 = __builtin_amdgcn_mfma_f32_16x16x32_bf16(ah1, xh[0][1], h0, 0, 0, 0);
            h1 = __builtin_amdgcn_mfma_f32_16x16x32_bf16(ah1, xh[1][1], h1, 0, 0, 0);
            p0 = __builtin_amdgcn_mfma_f32_16x16x32_bf16(al1, xh[0][1], p0, 0, 0, 0);
            p1 = __builtin_amdgcn_mfma_f32_16x16x32_bf16(al1, xh[1][1], p1, 0, 0, 0);
            q0 = __builtin_amdgcn_mfma_f32_16x16x32_bf16(ah1, xl[0][1], q0, 0, 0, 0);
            q1 = __builtin_amdgcn_mfma_f32_16x16x32_bf16(ah1, xl[1][1], q1, 0, 0, 0);

            f32x4 s0 = (h0 + p0) + q0;
            f32x4 s1 = (h1 + p1) + q1;

            const unsigned kb4 = (unsigned)((ktb + kt) * 4);
#define PACKMIN(ACC, NTI)                                                          \
            {                                                                      \
                unsigned u0 = ((__float_as_uint(ACC[0]) + 64u) & 0xFFFFFF80u) | (kb4 + 0); \
                unsigned u1 = ((__float_as_uint(ACC[1]) + 64u) & 0xFFFFFF80u) | (kb4 + 1); \
                unsigned u2 = ((__float_as_uint(ACC[2]) + 64u) & 0xFFFFFF80u) | (kb4 + 2); \
                unsigned u3 = ((__float_as_uint(ACC[3]) + 64u) & 0xFFFFFF80u) | (kb4 + 3); \
                float f0 = __uint_as_float(u0), f1 = __uint_as_float(u1);          \
                float f2 = __uint_as_float(u2), f3 = __uint_as_float(u3);          \
                float lo = fminf(f0, f1), hi = fmaxf(f0, f1);                      \
                pb2[NTI] = fminf(fminf(pb2[NTI], fmaxf(pb1[NTI], lo)), hi);        \
                pb1[NTI] = fminf(pb1[NTI], lo);                                    \
                lo = fminf(f2, f3); hi = fmaxf(f2, f3);                            \
                pb2[NTI] = fminf(fminf(pb2[NTI], fmaxf(pb1[NTI], lo)), hi);        \
                pb1[NTI] = fminf(pb1[NTI], lo);                                    \
            }
            PACKMIN(s0, 0)
            PACKMIN(s1, 1)
#undef PACKMIN
        }
    }

    // ---- per-nt: unpack, cross-lane merge, refine, gather, loss ----
    double dsum = 0.0;
#pragma unroll
    for (int nt = 0; nt < NT; ++nt) {
        unsigned u1 = __float_as_uint(pb1[nt]);
        unsigned u2 = __float_as_uint(pb2[nt]);
        int loc1 = u1 & 127, loc2 = u2 & 127;
        float b1 = __uint_as_float(u1 & 0xFFFFFF80u);
        float b2 = __uint_as_float(u2 & 0xFFFFFF80u);
        int i1 = ((loc1 >> 2) << 4) + lh * 4 + (loc1 & 3);
        int i2 = ((loc2 >> 2) << 4) + lh * 4 + (loc2 & 3);
        float xx = x2p[nt];
#pragma unroll
        for (int off = 16; off <= 32; off <<= 1) {
            float ob1 = __shfl_xor(b1, off, 64);
            int   oi1 = __shfl_xor(i1, off, 64);
            float ob2 = __shfl_xor(b2, off, 64);
            int   oi2 = __shfl_xor(i2, off, 64);
            float oxx = __shfl_xor(xx, off, 64);
            xx += oxx;
            bool to = lessidx(ob1, oi1, b1, i1);
            float w1 = to ? ob1 : b1;  int wi1 = to ? oi1 : i1;
            float l1 = to ? b1 : ob1;  int li1 = to ? i1 : oi1;
            float c2 = to ? ob2 : b2;  int ci2 = to ? oi2 : i2;
            bool t2 = lessidx(l1, li1, c2, ci2);
            b1 = w1; i1 = wi1;
            b2 = t2 ? l1 : c2; i2 = t2 ? li1 : ci2;
        }

        int bw = i1;
        if (lane < 16) {
            double md;
            if (b2 - b1 < 1.2e-2f) {
                const int n = nbase + nt * 16 + lane;
                const float4* xq = (const float4*)(x + (size_t)n * C_DIM);
                const float4* p1 = (const float4*)(emb + (size_t)i1 * C_DIM);
                const float4* p2 = (const float4*)(emb + (size_t)i2 * C_DIM);
                double s1 = 0.0, s2 = 0.0;
#pragma unroll
                for (int i = 0; i < 16; ++i) {
                    float4 xv = xq[i]; float4 a = p1[i]; float4 bq = p2[i];
                    double d;
                    d = (double)xv.x - (double)a.x;  s1 = fma(d, d, s1);
                    d = (double)xv.y - (double)a.y;  s1 = fma(d, d, s1);
                    d = (double)xv.z - (double)a.z;  s1 = fma(d, d, s1);
                    d = (double)xv.w - (double)a.w;  s1 = fma(d, d, s1);
                    d = (double)xv.x - (double)bq.x; s2 = fma(d, d, s2);
                    d = (double)xv.y - (double)bq.y; s2 = fma(d, d, s2);
                    d = (double)xv.z - (double)bq.z; s2 = fma(d, d, s2);
                    d = (double)xv.w - (double)bq.w; s2 = fma(d, d, s2);
                }
                if (s2 < s1 || (s1 == s2 && i2 < i1)) { bw = i2; md = s2; }
                else                                   { md = s1; }
            } else {
                md = (double)xx + (double)b1;
            }
            dsum += md;
        }

        // per-wave gather: 16 vectors x 16 float4 chunks, 4 iters of 64 lanes
        {
            const int v  = lane >> 2;
            const int c0 = lane & 3;
            const int w  = __shfl(bw, v);
            const size_t rowb = ((size_t)(nbase + nt * 16 + v)) * 16;
            const float4* ep = (const float4*)emb + (size_t)w * 16;
            float4* op = (float4*)out;
#pragma unroll
            for (int it = 0; it < 4; ++it) op[rowb + c0 + it * 4] = ep[c0 + it * 4];
        }
    }

    // ---- loss partial ----
#pragma unroll
    for (int off = 1; off <= 8; off <<= 1) dsum += __shfl_xor(dsum, off, 64);
    if (lane == 0) s_wsum[wid] = dsum;
    __syncthreads();
    if (tid == 0) {
        double t = 0.0;
#pragma unroll
        for (int i = 0; i < BLK / 64; ++i) t += s_wsum[i];
        partials[blockIdx.x] = t;
    }
}

__global__ __launch_bounds__(512) void vq_finalize(const double* __restrict__ partials,
                                                   float* __restrict__ out) {
    double v = partials[threadIdx.x];   // 512 partials
#pragma unroll
    for (int off = 32; off; off >>= 1) v += __shfl_down(v, off, 64);
    __shared__ double ls[8];
    const int lane = threadIdx.x & 63;
    const int wid  = threadIdx.x >> 6;
    if (lane == 0) ls[wid] = v;
    __syncthreads();
    if (threadIdx.x == 0) {
        double t = 0.0;
#pragma unroll
        for (int i = 0; i < 8; ++i) t += ls[i];
        double mean = t / (double)((size_t)NVEC * C_DIM);
        out[(size_t)NVEC * C_DIM] = (float)(1.25 * mean);
    }
}

extern "C" void kernel_launch(void* const* d_in, const int* in_sizes, int n_in,
                              void* d_out, int out_size, void* d_ws, size_t ws_size,
                              hipStream_t stream) {
    const float* x   = (const float*)d_in[0];
    const float* emb = (const float*)d_in[1];
    float* out = (float*)d_out;

    float*  e2       = (float*)((char*)d_ws + WS_E2);
    short*  ehi      = (short*)((char*)d_ws + WS_EHI);
    short*  elo      = (short*)((char*)d_ws + WS_ELO);
    double* partials = (double*)((char*)d_ws + WS_PART);

    vq_prep<<<8, 512, 0, stream>>>(emb, e2, ehi, elo);
    vq_main<<<GRID, BLK, 0, stream>>>(x, emb, e2, ehi, elo, out, partials);
    vq_finalize<<<1, 512, 0, stream>>>(partials, out);
}

// Round 8
// 49.224 us; speedup vs baseline: 1.0806x; 1.0806x over previous
//
#include <hip/hip_runtime.h>

// VectorQuantization: x (32,64,64,64) f32, embedding (512,64) f32
// out = [quantized_ste (8388608 f32)] ++ [loss (1 f32)]
//
// score[k,n] = e2[k] - 2*dot(e_k, x_n); argmin_k; gather; loss=1.25*mean dist.
// bf16 3-pass MFMA (hi*hi + lo*hi + hi*lo), packed top-2 + fp64 refine.
// Round 8: 2-state software pipeline (T15): phase(kt) = {ds_read(kt+1) |
// MFMA(kt) | PACKMIN(kt-1)} with named register sets -> no intra-phase deps.

#define C_DIM 64
#define K_EMB 512
#define NVEC (32 * 64 * 64)     // 131072
#define BLK 512                 // 8 waves
#define VPW 64                  // vectors per wave
#define NPB 512                 // vectors per block
#define GRID (NVEC / NPB)       // 256 = 1 block/CU
#define KT (K_EMB / 16)         // 32 k-tiles
#define NT 4                    // 16-vector groups per wave

typedef __attribute__((ext_vector_type(8))) short bf16x8;
typedef __attribute__((ext_vector_type(4))) float f32x4;

// ws layout (bytes)
#define WS_E2   0
#define WS_EHI  4096
#define WS_ELO  (4096 + 65536)
#define WS_PART (4096 + 2 * 65536)

__device__ inline unsigned short f2bf(float f) {
    unsigned u = __float_as_uint(f);
    u += 0x7FFF + ((u >> 16) & 1);   // RNE
    return (unsigned short)(u >> 16);
}
__device__ inline float bf2f(unsigned short h) {
    return __uint_as_float(((unsigned)h) << 16);
}
__device__ inline bool lessidx(float s, int i, float t, int j) {
    return (s < t) || (s == t && i < j);
}

// ---- prep: e2[k]; frag-linear bf16 hi/lo of (-2*emb) ----
// frag layout: region r = kt*2 + s (s = K-step), lane l holds 8 bf16 =
// A[row = kt*16 + (l&15)][c = 32*s + (l>>4)*8 + j], stored at (r*64+l)*8 shorts.
__global__ __launch_bounds__(512) void vq_prep(const float* __restrict__ emb,
                                               float* __restrict__ e2,
                                               short* __restrict__ ehi,
                                               short* __restrict__ elo) {
    const int t = blockIdx.x * 512 + threadIdx.x;   // 0..4095
    const int l = t & 63;
    const int kt2 = t >> 6;                         // kt*2 + s
    const int row = (kt2 >> 1) * 16 + (l & 15);
    const int cb  = (kt2 & 1) * 32 + (l >> 4) * 8;
    const float* src = emb + row * C_DIM + cb;
    bf16x8 vh, vl;
#pragma unroll
    for (int j = 0; j < 8; ++j) {
        float v = -2.0f * src[j];
        unsigned short h = f2bf(v);
        float hf = bf2f(h);
        unsigned short q = f2bf(v - hf);
        vh[j] = (short)h;
        vl[j] = (short)q;
    }
    *(bf16x8*)(ehi + (size_t)t * 8) = vh;
    *(bf16x8*)(elo + (size_t)t * 8) = vl;

    if (t < K_EMB) {
        const float* r = emb + t * C_DIM;
        float s = 0.f;
#pragma unroll
        for (int c = 0; c < C_DIM; ++c) s += r[c] * r[c];
        e2[t] = s;
    }
}

__global__ __launch_bounds__(BLK, 2) void vq_main(
    const float* __restrict__ x,
    const float* __restrict__ emb,
    const float* __restrict__ e2g,
    const short* __restrict__ ehi_g,
    const short* __restrict__ elo_g,
    float* __restrict__ out,
    double* __restrict__ partials)
{
    __shared__ __align__(16) short s_hi[K_EMB * C_DIM];  // 64 KB, frag-linear
    __shared__ __align__(16) short s_lo[K_EMB * C_DIM];  // 64 KB
    __shared__ __align__(16) float s_e2[K_EMB];          // 2 KB
    __shared__ double s_wsum[BLK / 64];

    const int tid  = threadIdx.x;
    const int lane = tid & 63;
    const int wid  = tid >> 6;
    const int lr   = lane & 15;
    const int lh   = lane >> 4;
    const int nbase = blockIdx.x * NPB + wid * VPW;

    // ---- x loads first (fly during staging) ----
    float4 xr[NT * 4];
#pragma unroll
    for (int nt = 0; nt < NT; ++nt) {
        const float* xp = x + (size_t)(nbase + nt * 16 + lr) * C_DIM;
#pragma unroll
        for (int s = 0; s < 2; ++s) {
            xr[nt * 4 + s * 2 + 0] = *(const float4*)(xp + s * 32 + lh * 8);
            xr[nt * 4 + s * 2 + 1] = *(const float4*)(xp + s * 32 + lh * 8 + 4);
        }
    }

    // ---- stage tables into LDS (linear copy, coalesced) ----
    {
        const float4* srch = (const float4*)ehi_g;
        const float4* srcl = (const float4*)elo_g;
        float4* dsth = (float4*)s_hi;
        float4* dstl = (float4*)s_lo;
#pragma unroll
        for (int i = 0; i < 8; ++i) dsth[tid + i * BLK] = srch[tid + i * BLK];
#pragma unroll
        for (int i = 0; i < 8; ++i) dstl[tid + i * BLK] = srcl[tid + i * BLK];
        if (tid < K_EMB) s_e2[tid] = e2g[tid];
    }
    __syncthreads();

    // ---- x -> B-fragments (hi/lo), x2 partials ----
    bf16x8 xh[NT][2], xl[NT][2];
    float x2p[NT];
#pragma unroll
    for (int nt = 0; nt < NT; ++nt) {
        x2p[nt] = 0.f;
#pragma unroll
        for (int s = 0; s < 2; ++s) {
            float4 a = xr[nt * 4 + s * 2 + 0];
            float4 b = xr[nt * 4 + s * 2 + 1];
            float vv[8] = {a.x, a.y, a.z, a.w, b.x, b.y, b.z, b.w};
#pragma unroll
            for (int j = 0; j < 8; ++j) {
                float v = vv[j];
                x2p[nt] += v * v;
                unsigned short h = f2bf(v);
                float hf = bf2f(h);
                unsigned short q = f2bf(v - hf);
                xh[nt][s][j] = (short)h;
                xl[nt][s][j] = (short)q;
            }
        }
    }

    // ---- pipelined k-loop ----
    float pb1[NT] = {1e30f, 1e30f, 1e30f, 1e30f};
    float pb2[NT] = {1e30f, 1e30f, 1e30f, 1e30f};

    const bf16x8* hb = (const bf16x8*)s_hi + lane;
    const bf16x8* lb = (const bf16x8*)s_lo + lane;

#define MFMA16 __builtin_amdgcn_mfma_f32_16x16x32_bf16

#define LOAD_FRAGS(KTI, FH0, FH1, FL0, FL1, EV)                  \
    FH0 = hb[(KTI) * 128]; FH1 = hb[(KTI) * 128 + 64];           \
    FL0 = lb[(KTI) * 128]; FL1 = lb[(KTI) * 128 + 64];           \
    EV  = *(const f32x4*)(s_e2 + (KTI) * 16 + lh * 4);

// 24 MFMAs, 4 independent chains, 6 deep, r4's exact pass order
#define DO_MFMA(FH0, FH1, FL0, FL1, EV, C0, C1, C2, C3)          \
    C0 = EV; C1 = EV; C2 = EV; C3 = EV;                          \
    C0 = MFMA16(FH0, xh[0][0], C0, 0, 0, 0);                     \
    C1 = MFMA16(FH0, xh[1][0], C1, 0, 0, 0);                     \
    C2 = MFMA16(FH0, xh[2][0], C2, 0, 0, 0);                     \
    C3 = MFMA16(FH0, xh[3][0], C3, 0, 0, 0);                     \
    C0 = MFMA16(FH1, xh[0][1], C0, 0, 0, 0);                     \
    C1 = MFMA16(FH1, xh[1][1], C1, 0, 0, 0);                     \
    C2 = MFMA16(FH1, xh[2][1], C2, 0, 0, 0);                     \
    C3 = MFMA16(FH1, xh[3][1], C3, 0, 0, 0);                     \
    C0 = MFMA16(FL0, xh[0][0], C0, 0, 0, 0);                     \
    C1 = MFMA16(FL0, xh[1][0], C1, 0, 0, 0);                     \
    C2 = MFMA16(FL0, xh[2][0], C2, 0, 0, 0);                     \
    C3 = MFMA16(FL0, xh[3][0], C3, 0, 0, 0);                     \
    C0 = MFMA16(FL1, xh[0][1], C0, 0, 0, 0);                     \
    C1 = MFMA16(FL1, xh[1][1], C1, 0, 0, 0);                     \
    C2 = MFMA16(FL1, xh[2][1], C2, 0, 0, 0);                     \
    C3 = MFMA16(FL1, xh[3][1], C3, 0, 0, 0);                     \
    C0 = MFMA16(FH0, xl[0][0], C0, 0, 0, 0);                     \
    C1 = MFMA16(FH0, xl[1][0], C1, 0, 0, 0);                     \
    C2 = MFMA16(FH0, xl[2][0], C2, 0, 0, 0);                     \
    C3 = MFMA16(FH0, xl[3][0], C3, 0, 0, 0);                     \
    C0 = MFMA16(FH1, xl[0][1], C0, 0, 0, 0);                     \
    C1 = MFMA16(FH1, xl[1][1], C1, 0, 0, 0);                     \
    C2 = MFMA16(FH1, xl[2][1], C2, 0, 0, 0);                     \
    C3 = MFMA16(FH1, xl[3][1], C3, 0, 0, 0);

#define PACKMIN(ACC, NTI, KB4)                                                 \
    {                                                                          \
        unsigned q0 = ((__float_as_uint(ACC[0]) + 64u) & 0xFFFFFF80u) | (KB4 + 0); \
        unsigned q1 = ((__float_as_uint(ACC[1]) + 64u) & 0xFFFFFF80u) | (KB4 + 1); \
        unsigned q2 = ((__float_as_uint(ACC[2]) + 64u) & 0xFFFFFF80u) | (KB4 + 2); \
        unsigned q3 = ((__float_as_uint(ACC[3]) + 64u) & 0xFFFFFF80u) | (KB4 + 3); \
        float f0 = __uint_as_float(q0), f1 = __uint_as_float(q1);              \
        float f2 = __uint_as_float(q2), f3 = __uint_as_float(q3);              \
        float lo = fminf(f0, f1), hi = fmaxf(f0, f1);                          \
        pb2[NTI] = fminf(fminf(pb2[NTI], fmaxf(pb1[NTI], lo)), hi);            \
        pb1[NTI] = fminf(pb1[NTI], lo);                                        \
        lo = fminf(f2, f3); hi = fmaxf(f2, f3);                                \
        pb2[NTI] = fminf(fminf(pb2[NTI], fmaxf(pb1[NTI], lo)), hi);            \
        pb1[NTI] = fminf(pb1[NTI], lo);                                        \
    }

    {
        bf16x8 a0h0, a0h1, a0l0, a0l1;   // frag set 0 (even kt)
        bf16x8 a1h0, a1h1, a1l0, a1l1;   // frag set 1 (odd kt)
        f32x4 ev0, ev1;
        f32x4 c00, c01, c02, c03;        // acc set 0 (even kt)
        f32x4 c10, c11, c12, c13;        // acc set 1 (odd kt)

        LOAD_FRAGS(0, a0h0, a0h1, a0l0, a0l1, ev0)
        LOAD_FRAGS(1, a1h0, a1h1, a1l0, a1l1, ev1)
        DO_MFMA(a0h0, a0h1, a0l0, a0l1, ev0, c00, c01, c02, c03)   // kt=0

        for (int kt = 1; kt <= KT - 3; kt += 2) {
            // phase odd kt: load kt+1 | MFMA(kt) | pack(kt-1)
            LOAD_FRAGS(kt + 1, a0h0, a0h1, a0l0, a0l1, ev0)
            DO_MFMA(a1h0, a1h1, a1l0, a1l1, ev1, c10, c11, c12, c13)
            {
                const unsigned kb4 = (unsigned)((kt - 1) * 4);
                PACKMIN(c00, 0, kb4) PACKMIN(c01, 1, kb4)
                PACKMIN(c02, 2, kb4) PACKMIN(c03, 3, kb4)
            }
            // phase even kt+1: load kt+2 | MFMA(kt+1) | pack(kt)
            LOAD_FRAGS(kt + 2, a1h0, a1h1, a1l0, a1l1, ev1)
            DO_MFMA(a0h0, a0h1, a0l0, a0l1, ev0, c00, c01, c02, c03)
            {
                const unsigned kb4 = (unsigned)(kt * 4);
                PACKMIN(c10, 0, kb4) PACKMIN(c11, 1, kb4)
                PACKMIN(c12, 2, kb4) PACKMIN(c13, 3, kb4)
            }
        }
        // tail: kt=31 MFMA | pack(30) | pack(31)
        DO_MFMA(a1h0, a1h1, a1l0, a1l1, ev1, c10, c11, c12, c13)
        {
            const unsigned kb4 = (unsigned)((KT - 2) * 4);
            PACKMIN(c00, 0, kb4) PACKMIN(c01, 1, kb4)
            PACKMIN(c02, 2, kb4) PACKMIN(c03, 3, kb4)
        }
        {
            const unsigned kb4 = (unsigned)((KT - 1) * 4);
            PACKMIN(c10, 0, kb4) PACKMIN(c11, 1, kb4)
            PACKMIN(c12, 2, kb4) PACKMIN(c13, 3, kb4)
        }
    }
#undef PACKMIN
#undef DO_MFMA
#undef LOAD_FRAGS
#undef MFMA16

    // ---- per-nt: unpack, cross-lane merge, refine, gather, loss ----
    double dsum = 0.0;
#pragma unroll
    for (int nt = 0; nt < NT; ++nt) {
        unsigned u1 = __float_as_uint(pb1[nt]);
        unsigned u2 = __float_as_uint(pb2[nt]);
        int loc1 = u1 & 127, loc2 = u2 & 127;
        float b1 = __uint_as_float(u1 & 0xFFFFFF80u);
        float b2 = __uint_as_float(u2 & 0xFFFFFF80u);
        int i1 = ((loc1 >> 2) << 4) + lh * 4 + (loc1 & 3);
        int i2 = ((loc2 >> 2) << 4) + lh * 4 + (loc2 & 3);
        float xx = x2p[nt];
#pragma unroll
        for (int off = 16; off <= 32; off <<= 1) {
            float ob1 = __shfl_xor(b1, off, 64);
            int   oi1 = __shfl_xor(i1, off, 64);
            float ob2 = __shfl_xor(b2, off, 64);
            int   oi2 = __shfl_xor(i2, off, 64);
            float oxx = __shfl_xor(xx, off, 64);
            xx += oxx;
            bool to = lessidx(ob1, oi1, b1, i1);
            float w1 = to ? ob1 : b1;  int wi1 = to ? oi1 : i1;
            float l1 = to ? b1 : ob1;  int li1 = to ? i1 : oi1;
            float c2 = to ? ob2 : b2;  int ci2 = to ? oi2 : i2;
            bool t2 = lessidx(l1, li1, c2, ci2);
            b1 = w1; i1 = wi1;
            b2 = t2 ? l1 : c2; i2 = t2 ? li1 : ci2;
        }

        int bw = i1;
        if (lane < 16) {
            double md;
            if (b2 - b1 < 1.2e-2f) {
                const int n = nbase + nt * 16 + lane;
                const float4* xq = (const float4*)(x + (size_t)n * C_DIM);
                const float4* p1 = (const float4*)(emb + (size_t)i1 * C_DIM);
                const float4* p2 = (const float4*)(emb + (size_t)i2 * C_DIM);
                double s1 = 0.0, s2 = 0.0;
#pragma unroll
                for (int i = 0; i < 16; ++i) {
                    float4 xv = xq[i]; float4 a = p1[i]; float4 bq = p2[i];
                    double d;
                    d = (double)xv.x - (double)a.x;  s1 = fma(d, d, s1);
                    d = (double)xv.y - (double)a.y;  s1 = fma(d, d, s1);
                    d = (double)xv.z - (double)a.z;  s1 = fma(d, d, s1);
                    d = (double)xv.w - (double)a.w;  s1 = fma(d, d, s1);
                    d = (double)xv.x - (double)bq.x; s2 = fma(d, d, s2);
                    d = (double)xv.y - (double)bq.y; s2 = fma(d, d, s2);
                    d = (double)xv.z - (double)bq.z; s2 = fma(d, d, s2);
                    d = (double)xv.w - (double)bq.w; s2 = fma(d, d, s2);
                }
                if (s2 < s1 || (s1 == s2 && i2 < i1)) { bw = i2; md = s2; }
                else                                   { md = s1; }
            } else {
                md = (double)xx + (double)b1;
            }
            dsum += md;
        }

        // per-wave gather: 16 vectors x 16 float4 chunks, 4 iters of 64 lanes
        {
            const int v  = lane >> 2;
            const int c0 = lane & 3;
            const int w  = __shfl(bw, v);
            const size_t rowb = ((size_t)(nbase + nt * 16 + v)) * 16;
            const float4* ep = (const float4*)emb + (size_t)w * 16;
            float4* op = (float4*)out;
#pragma unroll
            for (int it = 0; it < 4; ++it) op[rowb + c0 + it * 4] = ep[c0 + it * 4];
        }
    }

    // ---- loss partial ----
#pragma unroll
    for (int off = 1; off <= 8; off <<= 1) dsum += __shfl_xor(dsum, off, 64);
    if (lane == 0) s_wsum[wid] = dsum;
    __syncthreads();
    if (tid == 0) {
        double t = 0.0;
#pragma unroll
        for (int i = 0; i < BLK / 64; ++i) t += s_wsum[i];
        partials[blockIdx.x] = t;
    }
}

__global__ __launch_bounds__(256) void vq_finalize(const double* __restrict__ partials,
                                                   float* __restrict__ out) {
    double v = partials[threadIdx.x];   // 256 partials
#pragma unroll
    for (int off = 32; off; off >>= 1) v += __shfl_down(v, off, 64);
    __shared__ double ls[4];
    const int lane = threadIdx.x & 63;
    const int wid  = threadIdx.x >> 6;
    if (lane == 0) ls[wid] = v;
    __syncthreads();
    if (threadIdx.x == 0) {
        double t = ls[0] + ls[1] + ls[2] + ls[3];
        double mean = t / (double)((size_t)NVEC * C_DIM);
        out[(size_t)NVEC * C_DIM] = (float)(1.25 * mean);
    }
}

extern "C" void kernel_launch(void* const* d_in, const int* in_sizes, int n_in,
                              void* d_out, int out_size, void* d_ws, size_t ws_size,
                              hipStream_t stream) {
    const float* x   = (const float*)d_in[0];
    const float* emb = (const float*)d_in[1];
    float* out = (float*)d_out;

    float*  e2       = (float*)((char*)d_ws + WS_E2);
    short*  ehi      = (short*)((char*)d_ws + WS_EHI);
    short*  elo      = (short*)((char*)d_ws + WS_ELO);
    double* partials = (double*)((char*)d_ws + WS_PART);

    vq_prep<<<8, 512, 0, stream>>>(emb, e2, ehi, elo);
    vq_main<<<GRID, BLK, 0, stream>>>(x, emb, e2, ehi, elo, out, partials);
    vq_finalize<<<1, 256, 0, stream>>>(partials, out);
}